// Round 1
// baseline (829.098 us; speedup 1.0000x reference)
//
#include <hip/hip_runtime.h>
#include <cstdint>
#include <cstddef>

typedef __bf16  bf16x8  __attribute__((ext_vector_type(8)));
typedef float   f32x4   __attribute__((ext_vector_type(4)));

constexpr int P_PARTS     = 62;
constexpr int N_TOK       = 8192;
constexpr int C_IN        = 128;
constexpr int C_OUT       = 256;
constexpr int ROWS_PER_WG = 512;                       // rows per block
constexpr int ROWS_ITER   = 64;                        // rows per iteration
constexpr int N_ITER      = ROWS_PER_WG / ROWS_ITER;   // 8
constexpr int WG_PER_PART = N_TOK / ROWS_PER_WG;       // 16
constexpr int NWG         = P_PARTS * WG_PER_PART;     // 992 = 8 * 124 (divisible by 8)
constexpr float LN_EPS    = 1e-5f;

// Native f32->bf16 (RNE); compiler emits v_cvt_pk_bf16_f32 pairs.
__device__ __forceinline__ bf16x8 cvt8(f32x4 a, f32x4 b) {
    bf16x8 r;
    #pragma unroll
    for (int j = 0; j < 4; ++j) {
        r[j]     = (__bf16)a[j];
        r[j + 4] = (__bf16)b[j];
    }
    return r;
}

// One butterfly step of a 16-lane sum on the VALU pipe (DPP row rotate),
// replacing ds_swizzle-based __shfl_xor. row_ror stays within each 16-lane row.
template <int CTRL>
__device__ __forceinline__ float ror16_add(float s) {
    int t = __builtin_amdgcn_update_dpp(0, __float_as_int(s), CTRL, 0xf, 0xf, false);
    return s + __int_as_float(t);
}
__device__ __forceinline__ float red16(float s) {
    s = ror16_add<0x128>(s);   // row_ror:8
    s = ror16_add<0x124>(s);   // row_ror:4
    s = ror16_add<0x122>(s);   // row_ror:2
    s = ror16_add<0x121>(s);   // row_ror:1
    return s;                  // all 16 lanes hold the group sum
}

// Fused per-part FC (x[P,N,128] @ W[P,256,128]^T) + LayerNorm(256).
// x A-fragments are read DIRECTLY from global: all 4 waves of a block share
// one 32 KB tile, which L1 (32 KB/CU) + L2 serve — the old LDS staging round
// trip, its conversions and 2 of its 3 barriers are deleted. One barrier per
// iteration remains (cross-wave LN stats), with double-buffered stats so no
// trailing barrier is needed.
extern "C" __global__ void __launch_bounds__(256, 3)
fused_fc_ln(const float* __restrict__ x, const float* __restrict__ Wt,
            const float* __restrict__ gamma, const float* __restrict__ beta,
            float* __restrict__ out)
{
    __shared__ __align__(16) float psum[2][ROWS_ITER][4];
    __shared__ __align__(16) float psq [2][ROWS_ITER][4];

    const int tid  = threadIdx.x;
    const int wv   = tid >> 6;       // wave 0..3 -> owns cols [wv*64, wv*64+64)
    const int lane = tid & 63;
    const int quad = lane >> 4;      // 0..3 (A/B k-chunk; C/D row group)
    const int l16  = lane & 15;

    // XCD-bijective swizzle: blockIdx round-robins XCDs; give each XCD a
    // contiguous 124-block slice so a part's 16 blocks share one L2 (W reuse).
    const int wg   = (blockIdx.x & 7) * (NWG / 8) + (blockIdx.x >> 3);
    const int part = wg >> 4;            // WG_PER_PART == 16
    const int rb   = wg & 15;
    const long rowBase = (long)part * N_TOK + (long)rb * ROWS_PER_WG;

    // ---- W fragments for this wave's 64 channels: fp32 -> bf16, in VGPRs ----
    // B-operand layout: n = lane&15, k = quad*8 + j
    bf16x8 bfrag[4][4];              // [colTile][kChunk]
    float g[4], bt[4];
    #pragma unroll
    for (int ct = 0; ct < 4; ++ct) {
        const int d = wv * 64 + ct * 16 + l16;
        g[ct]  = gamma[d];
        bt[ct] = beta[d];
        const float* wp = Wt + ((size_t)part * C_OUT + d) * C_IN + quad * 8;
        #pragma unroll
        for (int kk = 0; kk < 4; ++kk) {
            const f32x4* p4 = (const f32x4*)(wp + kk * 32);
            bfrag[ct][kk] = cvt8(p4[0], p4[1]);
        }
    }

    const float* xblk = x   + rowBase * C_IN;
    float*       oblk = out + rowBase * C_OUT;
    const float  invC = 1.0f / C_OUT;

    for (int it = 0; it < N_ITER; ++it) {
        const float* xt = xblk + (size_t)it * (ROWS_ITER * C_IN);

        f32x4 acc[4][4];                       // [rowTile][colTile]
        #pragma unroll
        for (int rt = 0; rt < 4; ++rt)
            #pragma unroll
            for (int ct = 0; ct < 4; ++ct)
                acc[rt][ct] = f32x4{0.f, 0.f, 0.f, 0.f};

        // ---- MFMA: A-frags direct from global (coalesced 128B row segments) ----
        // A-operand: m = lane&15, k = quad*8 + j; K=128 split as kk*32 + quad*8
        #pragma unroll
        for (int rt = 0; rt < 4; ++rt) {
            const float* xr = xt + (size_t)(rt * 16 + l16) * C_IN + quad * 8;
            f32x4 lo[4], hi[4];
            #pragma unroll
            for (int kk = 0; kk < 4; ++kk) {   // issue all 8 loads first (MLP)
                const f32x4* p = (const f32x4*)(xr + kk * 32);
                lo[kk] = p[0];
                hi[kk] = p[1];
            }
            #pragma unroll
            for (int kk = 0; kk < 4; ++kk) {
                const bf16x8 af = cvt8(lo[kk], hi[kk]);
                #pragma unroll
                for (int ct = 0; ct < 4; ++ct)
                    acc[rt][ct] = __builtin_amdgcn_mfma_f32_16x16x32_bf16(
                        af, bfrag[ct][kk], acc[rt][ct], 0, 0, 0);
            }
        }

        // ---- LN partials: 16-lane DPP reduce (VALU), one LDS write per row ----
        // C/D layout: col = lane&15, row = quad*4 + reg
        const int sb = it & 1;
        #pragma unroll
        for (int rt = 0; rt < 4; ++rt) {
            #pragma unroll
            for (int rg = 0; rg < 4; ++rg) {
                const float a0 = acc[rt][0][rg], a1 = acc[rt][1][rg];
                const float a2 = acc[rt][2][rg], a3 = acc[rt][3][rg];
                float s  = (a0 + a1) + (a2 + a3);
                float s2 = (a0 * a0 + a1 * a1) + (a2 * a2 + a3 * a3);
                s  = red16(s);
                s2 = red16(s2);
                if (l16 == 0) {
                    const int row = rt * 16 + quad * 4 + rg;
                    psum[sb][row][wv] = s;
                    psq [sb][row][wv] = s2;
                }
            }
        }
        __syncthreads();   // the only barrier per iteration

        // ---- finalize stats per lane (redundant, VALU-cheap) + store ----
        float* od = oblk + (size_t)it * (ROWS_ITER * C_OUT);
        #pragma unroll
        for (int rt = 0; rt < 4; ++rt) {
            #pragma unroll
            for (int rg = 0; rg < 4; ++rg) {
                const int row = rt * 16 + quad * 4 + rg;
                const f32x4 ps = *(const f32x4*)&psum[sb][row][0];  // broadcast read
                const f32x4 pq = *(const f32x4*)&psq [sb][row][0];
                const float s  = (ps[0] + ps[1]) + (ps[2] + ps[3]);
                const float q  = (pq[0] + pq[1]) + (pq[2] + pq[3]);
                const float mu = s * invC;
                const float rs = rsqrtf(q * invC - mu * mu + LN_EPS);
                float* orow = od + (size_t)row * C_OUT + wv * 64 + l16;
                #pragma unroll
                for (int ct = 0; ct < 4; ++ct)
                    __builtin_nontemporal_store(
                        (acc[rt][ct][rg] - mu) * rs * g[ct] + bt[ct],
                        orow + ct * 16);
            }
        }
        // stats are double-buffered (sb flips): a leading wave's next-iter
        // writes go to psum[!sb], so no trailing barrier is required.
    }
}

extern "C" void kernel_launch(void* const* d_in, const int* in_sizes, int n_in,
                              void* d_out, int out_size, void* d_ws, size_t ws_size,
                              hipStream_t stream) {
    const float* x     = (const float*)d_in[0];
    const float* Wt    = (const float*)d_in[1];
    const float* gamma = (const float*)d_in[2];
    const float* beta  = (const float*)d_in[3];
    float* out = (float*)d_out;
    (void)in_sizes; (void)n_in; (void)d_ws; (void)ws_size; (void)out_size;
    fused_fc_ln<<<dim3(NWG), dim3(256), 0, stream>>>(x, Wt, gamma, beta, out);
}